// Round 17
// baseline (123.525 us; speedup 1.0000x reference)
//
#include <hip/hip_runtime.h>
#include <hip/hip_fp16.h>
#include <stdint.h>

#define M_TOTAL 16384
#define DIMS    64
#define CDIM    64
#define HID     100
#define ROWS    32
#define LOG2E   1.4426950408889634f
#define LN2     0.6931471805599453f

typedef __bf16 bf16x8 __attribute__((ext_vector_type(8)));
typedef float  f32x4  __attribute__((ext_vector_type(4)));

// W2 ws layout: [d][cn 0..6][kg 0..13][col16][8] (bf16); w,h cols pre-scaled by log2(e)
#define BKG        14
#define CN_STRIDE  (BKG*16*8)        // 1792
#define DIM_STRIDE (7*CN_STRIDE)     // 12544
#define W2M_ELEMS  (DIMS*DIM_STRIDE) // 802816
#define B2ALL_ELEMS (DIMS*128)       // 8192 f32
#define W1M_ELEMS  (3*7*8*16*8)      // 21504 bf16: [mat][cn][kg8][col16][8]
#define B1_ELEMS   (3*112)           // 336 f32
#define W2M_OFF   0
#define B2ALL_OFF (W2M_ELEMS*2)                  // 1605632
#define W1M_OFF   (B2ALL_OFF + B2ALL_ELEMS*4)    // 1638400
#define B1_OFF    (W1M_OFF + W1M_ELEMS*2)        // 1681408
#define PART_OFF  1682944                        // 2*16384 f32

__device__ __forceinline__ uint16_t f2bf(float f) {
  uint32_t u = __float_as_uint(f);
  return (uint16_t)((u + 0x8000u) >> 16);
}

__global__ void repack_kernel(
    const float* __restrict__ wW2, const float* __restrict__ wb2,
    const float* __restrict__ hW2, const float* __restrict__ hb2,
    const float* __restrict__ sW2, const float* __restrict__ sb2,
    const float* __restrict__ wW1, const float* __restrict__ hW1,
    const float* __restrict__ sW1,
    const float* __restrict__ wb1, const float* __restrict__ hb1,
    const float* __restrict__ sb1,
    uint16_t* __restrict__ W2m, float* __restrict__ b2all,
    uint16_t* __restrict__ W1m, float* __restrict__ b1all)
{
  int i = blockIdx.x * 256 + threadIdx.x;
  if (i < W2M_ELEMS) {
    int j  = i & 7;
    int c  = (i >> 3) & 15;
    int t  = i >> 7;
    int kg = t % BKG;
    int t2 = t / BKG;
    int cn = t2 % 7;
    int d  = t2 / 7;
    int k   = kg*8 + j;
    int col = cn*16 + c;
    float v = 0.f;
    if (k < HID) {
      if (col < 32)      v = wW2[k*2048 + d*32 + col] * LOG2E;
      else if (col < 64) v = hW2[k*2048 + d*32 + (col-32)] * LOG2E;
      else if (col < 97) v = sW2[k*2112 + d*33 + (col-64)];
    }
    W2m[i] = f2bf(v);
    return;
  }
  i -= W2M_ELEMS;
  if (i < B2ALL_ELEMS) {
    int c = i & 127;
    int d = i >> 7;
    float v = 0.f;
    if (c < 32)      v = wb2[d*32 + c] * LOG2E;
    else if (c < 64) v = hb2[d*32 + (c-32)] * LOG2E;
    else if (c < 97) v = sb2[d*33 + (c-64)];
    b2all[i] = v;
    return;
  }
  i -= B2ALL_ELEMS;
  if (i < W1M_ELEMS) {
    int jj = i & 7;
    int c  = (i >> 3) & 15;
    int kg = (i >> 7) & 7;
    int t  = i >> 10;         // mat*7 + cn
    int cn = t % 7;
    int mat = t / 7;
    int j = cn*16 + c;        // hidden unit
    int k = kg*8 + jj;        // cond dim
    const float* W1 = (mat == 0) ? wW1 : (mat == 1) ? hW1 : sW1;
    W1m[i] = f2bf((j < HID) ? W1[k*HID + j] : 0.f);
    return;
  }
  i -= W1M_ELEMS;
  if (i < B1_ELEMS) {
    int mat = i / 112, col = i % 112;
    const float* b1 = (mat == 0) ? wb1 : (mat == 1) ? hb1 : sb1;
    b1all[i] = (col < HID) ? b1[col] : 0.f;
  }
}

__global__ void ladj_reduce(const float* __restrict__ part, float* __restrict__ LADJ) {
  int i = blockIdx.x * 256 + threadIdx.x;
  if (i < M_TOTAL) LADJ[i] = LN2 * (part[i] + part[M_TOTAL + i]);
}

__global__ __launch_bounds__(256, 3)
void spline_main(
    const float* __restrict__ X, const float* __restrict__ C,
    const int* __restrict__ pmask,
    const uint16_t* __restrict__ W2m, const float* __restrict__ b2all,
    const uint16_t* __restrict__ W1m, const float* __restrict__ b1all,
    float* __restrict__ Y, float* __restrict__ part)
{
  __shared__ union {
    struct { float cond_s[ROWS*68]; uint16_t m2scr[16*ROWS*8]; } p;  // 8704 + 8192
    __half Ls[4][ROWS*100];                                          // 25600 B
  } U;
  __shared__ uint16_t At[2*16*ROWS*8];  // 16384 B: mats 0,1 (16 kg), persistent
  __shared__ float LjLds[4][ROWS];      // 512 B   (total 42496 B -> 3 blocks/CU @128KB)

  const int tid = threadIdx.x;
  const int rg = blockIdx.x >> 1;
  const int dhalf = blockIdx.x & 1;
  const int r0 = rg * ROWS;
  const int lane = tid & 63, wv = tid >> 6;
  const int l15 = lane & 15, lkg = lane >> 4;
  const int hb = lane >> 5;          // 0: widths pipe, 1: heights pipe
  const int srow = lane & 31;

  // ---- phase 0: stage cond tile ----
  for (int i = tid; i < ROWS*CDIM; i += 256) {
    int r = i >> 6, c = i & 63;
    U.p.cond_s[r*68 + c] = C[(size_t)(r0 + r)*CDIM + c];
  }
  __syncthreads();

  // ---- phase 1: hidden = silu(cond@W1+b1) via MFMA -> At (mats 0,1) / m2scr (mat 2) ----
  {
    bf16x8 cf[2][2];
#pragma unroll
    for (int m = 0; m < 2; ++m)
#pragma unroll
      for (int ks = 0; ks < 2; ++ks) {
        const float* cp = &U.p.cond_s[(m*16 + l15)*68 + ks*32 + lkg*8];
        float4 c0 = *(const float4*)cp;
        float4 c1 = *(const float4*)(cp + 4);
        union { uint16_t u[8]; bf16x8 v; } tmp;
        tmp.u[0]=f2bf(c0.x); tmp.u[1]=f2bf(c0.y); tmp.u[2]=f2bf(c0.z); tmp.u[3]=f2bf(c0.w);
        tmp.u[4]=f2bf(c1.x); tmp.u[5]=f2bf(c1.y); tmp.u[6]=f2bf(c1.z); tmp.u[7]=f2bf(c1.w);
        cf[m][ks] = tmp.v;
      }
    for (int t = wv; t < 21; t += 4) {
      int mat = t / 7, cn = t % 7;
      const uint16_t* Wb = W1m + (size_t)(mat*7 + cn)*1024;
      bf16x8 wf[2];
#pragma unroll
      for (int ks = 0; ks < 2; ++ks)
        wf[ks] = *(const bf16x8*)&Wb[(ks*4 + lkg)*128 + l15*8];
      f32x4 h0 = {0.f,0.f,0.f,0.f}, h1 = {0.f,0.f,0.f,0.f};
#pragma unroll
      for (int ks = 0; ks < 2; ++ks) {
        h0 = __builtin_amdgcn_mfma_f32_16x16x32_bf16(cf[0][ks], wf[ks], h0, 0, 0, 0);
        h1 = __builtin_amdgcn_mfma_f32_16x16x32_bf16(cf[1][ks], wf[ks], h1, 0, 0, 0);
      }
      float bb = b1all[mat*112 + cn*16 + l15];
      int j = cn*16 + l15;
      uint16_t* dst = (mat < 2) ? &At[mat*4096 + (j >> 3)*256 + (j & 7)]
                                : &U.p.m2scr[(j >> 3)*256 + (j & 7)];
#pragma unroll
      for (int r = 0; r < 4; ++r) {
        float a0 = h0[r] + bb;
        float v0 = a0 * __builtin_amdgcn_rcpf(1.f + __builtin_amdgcn_exp2f(-LOG2E*a0));
        dst[(lkg*4 + r)*8] = f2bf(v0);
        float a1 = h1[r] + bb;
        float v1 = a1 * __builtin_amdgcn_rcpf(1.f + __builtin_amdgcn_exp2f(-LOG2E*a1));
        dst[(16 + lkg*4 + r)*8] = f2bf(v1);
      }
    }
    // zero-fill kg 14,15 (K-padding: A must be 0 there) for At mats 0,1 and m2scr
    for (int i2 = tid; i2 < 768; i2 += 256) {
      int reg = i2 >> 8, q = i2 & 255;
      uint32_t* z = (reg < 2) ? (uint32_t*)&At[reg*4096 + 14*256]
                              : (uint32_t*)&U.p.m2scr[14*256];
      z[q] = 0u;
    }
  }
  __syncthreads();   // At + m2scr complete

  // ---- hoist mat-2 A fragments into registers (32 VGPR) ----
  bf16x8 af2[2][4];
#pragma unroll
  for (int m = 0; m < 2; ++m)
#pragma unroll
    for (int ks = 0; ks < 4; ++ks)
      af2[m][ks] = *(const bf16x8*)&U.p.m2scr[(ks*4 + lkg)*256 + (m*16 + l15)*8];
  __syncthreads();   // hoist reads done -> Ls region (incl. m2scr bytes) writable

  __half* LsW = &U.Ls[wv][0];
  const int dbase = dhalf*32 + wv*8;
  float ladj2 = 0.f;
  float xq = 0.f; int pq = 0;

  // ---- spline: binary-descent binsearch + tree-path prefix + LDS leaf gather ----
  auto SPLINE = [&](int d, float xv, int pm) {
    const __half* Lr = LsW + srow*100 + hb*32;
    float e[32];
#pragma unroll
    for (int q = 0; q < 16; ++q) {
      __half2 hp = *(const __half2*)(Lr + 2*q);
      float2 f2 = __half22float2(hp);
      e[2*q] = f2.x; e[2*q+1] = f2.y;
    }
    // partial-sum tree (levels kept)
    float t2[16], t4[8], t8[4], t16[2];
#pragma unroll
    for (int k = 0; k < 16; ++k) t2[k] = e[2*k] + e[2*k+1];
#pragma unroll
    for (int k = 0; k < 8; ++k)  t4[k] = t2[2*k] + t2[2*k+1];
#pragma unroll
    for (int k = 0; k < 4; ++k)  t8[k] = t4[2*k] + t4[2*k+1];
    t16[0] = t8[0] + t8[1]; t16[1] = t8[2] + t8[3];
    float S = t16[0] + t16[1];
    float rs = __builtin_amdgcn_rcpf(S);
    float Aa = (xv + 1.f) * 0.7352941176470588f * S;   // (x+1)/(2*0.68) * S
    float Uq = 0.014705882352941176f * S;              // 0.01/0.68 * S

    // 5-level binary descent: predicate prefix(c) <= Aa - c*Uq is monotone in c
    float T = Aa, p = 0.f, fidx;
    {
      float A = fmaf(-16.f, Uq, T);
      bool c4 = t16[0] <= A;
      p = c4 ? t16[0] : p;  T = c4 ? A : T;

      float n8 = c4 ? t8[2] : t8[0];
      A = fmaf(-8.f, Uq, T);
      float tt = p + n8;
      bool c3 = tt <= A;
      p = c3 ? tt : p;  T = c3 ? A : T;

      float n4 = c4 ? (c3 ? t4[6] : t4[4]) : (c3 ? t4[2] : t4[0]);
      A = fmaf(-4.f, Uq, T);
      tt = p + n4;
      bool c2 = tt <= A;
      p = c2 ? tt : p;  T = c2 ? A : T;

      float n2 = c4 ? (c3 ? (c2 ? t2[14] : t2[12]) : (c2 ? t2[10] : t2[8]))
                    : (c3 ? (c2 ? t2[6]  : t2[4])  : (c2 ? t2[2]  : t2[0]));
      A = fmaf(-2.f, Uq, T);
      tt = p + n2;
      bool c1 = tt <= A;
      p = c1 ? tt : p;  T = c1 ? A : T;

      float n1 = c4 ? (c3 ? (c2 ? (c1 ? e[30] : e[28]) : (c1 ? e[26] : e[24]))
                          : (c2 ? (c1 ? e[22] : e[20]) : (c1 ? e[18] : e[16])))
                    : (c3 ? (c2 ? (c1 ? e[14] : e[12]) : (c1 ? e[10] : e[8]))
                          : (c2 ? (c1 ? e[6]  : e[4])  : (c1 ? e[2]  : e[0])));
      A = fmaf(-1.f, Uq, T);
      bool c0 = (p + n1) <= A;
      fidx = (c4 ? 16.f : 0.f) + (c3 ? 8.f : 0.f) + (c2 ? 4.f : 0.f)
           + (c1 ? 2.f : 0.f) + (c0 ? 1.f : 0.f);
    }
    // broadcast lo-lane idx to both pipes
    float idxu = __shfl(fidx, srow);
    int idxi = (int)idxu;
    // bit extract
    bool B4 = idxu >= 15.5f; float u = B4 ? idxu - 16.f : idxu;
    bool B3 = u >= 7.5f;  u = B3 ? u - 8.f : u;
    bool B2 = u >= 3.5f;  u = B2 ? u - 4.f : u;
    bool B1 = u >= 1.5f;  u = B1 ? u - 2.f : u;
    bool B0 = u >= 0.5f;
    // tree-path prefix assembly at idxu (both pipes, own data)
    float Psel = B4 ? t16[0] : 0.f;
    float q8 = B4 ? t8[2] : t8[0];
    Psel = B3 ? Psel + q8 : Psel;
    float q4 = B4 ? (B3 ? t4[6] : t4[4]) : (B3 ? t4[2] : t4[0]);
    Psel = B2 ? Psel + q4 : Psel;
    float q2 = B4 ? (B3 ? (B2 ? t2[14] : t2[12]) : (B2 ? t2[10] : t2[8]))
                  : (B3 ? (B2 ? t2[6]  : t2[4])  : (B2 ? t2[2]  : t2[0]));
    Psel = B1 ? Psel + q2 : Psel;
    // leaf pair via one dynamic LDS gather: {e[idx&~1], e[idx|1]}
    float2 ep = __half22float2(*(const __half2*)(Lr + (idxi & ~1)));
    float q1e = ep.x, q1o = ep.y;
    Psel = B0 ? Psel + q1e : Psel;
    float esel = B0 ? q1o : q1e;

    float cK = fmaf(0.02f, idxu, -1.f) + 1.36f*rs*Psel;
    float wK = (idxu > 30.5f) ? (1.f - cK) : fmaf(1.36f*rs, esel, 0.02f);
    // slope: lo takes d[idx], hi takes d[idx+1] (periodic tie at idx==31)
    int off = 64 + idxi + hb;
    if (hb && idxi == 31) off = pm ? 64 : 96;
    float sl = __half2float(LsW[srow*100 + off]);
    float dkv = fmaf(LN2, __builtin_amdgcn_logf(1.f + __builtin_amdgcn_exp2f(LOG2E*sl)), 0.01f);
    // exchange: lo receives hi's (chk, hk, dk1)
    float cO = __shfl_xor(cK, 32);
    float wO = __shfl_xor(wK, 32);
    float dO = __shfl_xor(dkv, 32);
    float cwk = cK, wk = wK, dk = dkv, chk = cO, hk = wO, dk1 = dO;
    float rw = __builtin_amdgcn_rcpf(wk);
    float th = (xv - cwk)*rw;
    float delta = hk*rw;
    float omt = 1.f - th, t1m = th*omt, th2 = th*th;
    float denom = fmaf(dk1 + dk - 2.f*delta, t1m, delta);
    float rden = __builtin_amdgcn_rcpf(denom);
    float yv = fmaf(hk*fmaf(delta, th2, dk*t1m), rden, chk);
    float dn2 = fmaf(dk1, th2, fmaf(2.f*delta, t1m, dk*omt*omt));
    float tq = delta * rden;
    ladj2 += __builtin_amdgcn_logf(tq*tq*dn2);   // = 2log(delta)-2log(denom)+log(dn2)
    if (!hb) Y[(size_t)(r0 + srow)*DIMS + d] = yv;
  };

  // ---- A-frag loader (mats 0,1 from At, 16-kg layout) ----
  auto LOADA = [&](bf16x8 (&a2)[2][4], int mat) {
#pragma unroll
    for (int m = 0; m < 2; ++m)
#pragma unroll
      for (int ks = 0; ks < 4; ++ks)
        a2[m][ks] = *(const bf16x8*)&At[mat*4096 + (ks*4 + lkg)*256 + (m*16 + l15)*8];
  };

  // ---- per-cn GEMM tile: 8 MFMA + epilogue (f16 store) ----
  auto DO = [&](const bf16x8 (&afm)[2][4], const bf16x8 (&B)[4],
                float bb, int col, bool doexp) {
    f32x4 a0 = {bb,bb,bb,bb}, a1 = {bb,bb,bb,bb};
#pragma unroll
    for (int ks = 0; ks < 4; ++ks)
      a0 = __builtin_amdgcn_mfma_f32_16x16x32_bf16(afm[0][ks], B[ks], a0, 0, 0, 0);
#pragma unroll
    for (int ks = 0; ks < 4; ++ks)
      a1 = __builtin_amdgcn_mfma_f32_16x16x32_bf16(afm[1][ks], B[ks], a1, 0, 0, 0);
    if (doexp) {
#pragma unroll
      for (int r = 0; r < 4; ++r) {
        a0[r] = __builtin_amdgcn_exp2f(a0[r]);
        a1[r] = __builtin_amdgcn_exp2f(a1[r]);
      }
    }
    if (col < 97) {
#pragma unroll
      for (int r = 0; r < 4; ++r) {
        LsW[(lkg*4 + r)*100 + col]      = __float2half(a0[r]);
        LsW[(16 + lkg*4 + r)*100 + col] = __float2half(a1[r]);
      }
    }
  };

  // ---- main loop: 8 dims per wave, no barriers, 3-deep B pipeline ----
#pragma unroll 1
  for (int dd = 0; dd < 8; ++dd) {
    const int d = dbase + dd;
    const uint16_t* Bd = W2m + (size_t)d*DIM_STRIDE;
    auto LOADB = [&](bf16x8 (&dst)[4], int cn) {
#pragma unroll
      for (int ks = 0; ks < 4; ++ks) {
        int kgb = ks*4 + lkg; kgb = (kgb > 13) ? 13 : kgb;
        dst[ks] = *(const bf16x8*)&Bd[cn*CN_STRIDE + kgb*128 + l15*8];
      }
    };
    bf16x8 bA[4], bB[4], bC[4];
    LOADB(bA, 0); LOADB(bB, 1); LOADB(bC, 2);
    float bbv[7];
#pragma unroll
    for (int cn = 0; cn < 7; ++cn) bbv[cn] = b2all[d*128 + cn*16 + l15];
    float xn = X[(size_t)(r0 + srow)*DIMS + d];
    int pn = pmask[d];

    if (dd > 0) SPLINE(d - 1, xq, pq);   // hides B-load latency
    xq = xn; pq = pn;

    bf16x8 afc[2][4];
    LOADA(afc, 0);
    DO(afc, bA, bbv[0], 0*16 + l15, true);  LOADB(bA, 3);
    DO(afc, bB, bbv[1], 1*16 + l15, true);  LOADB(bB, 4);
    LOADA(afc, 1);
    DO(afc, bC, bbv[2], 2*16 + l15, true);  LOADB(bC, 5);
    DO(afc, bA, bbv[3], 3*16 + l15, true);  LOADB(bA, 6);
    DO(af2, bB, bbv[4], 4*16 + l15, false);
    DO(af2, bC, bbv[5], 5*16 + l15, false);
    DO(af2, bA, bbv[6], 6*16 + l15, false);
  }
  SPLINE(dbase + 7, xq, pq);

  if (!hb) LjLds[wv][srow] = ladj2;
  __syncthreads();
  if (tid < ROWS)
    part[dhalf*M_TOTAL + r0 + tid] =
      (LjLds[0][tid] + LjLds[1][tid]) + (LjLds[2][tid] + LjLds[3][tid]);
}

extern "C" void kernel_launch(void* const* d_in, const int* in_sizes, int n_in,
                              void* d_out, int out_size, void* d_ws, size_t ws_size,
                              hipStream_t stream) {
  const float* x     = (const float*)d_in[0];
  const float* cond  = (const float*)d_in[1];
  const int*   pmask = (const int*)d_in[2];
  const float* wW1 = (const float*)d_in[3];
  const float* wb1 = (const float*)d_in[4];
  const float* wW2 = (const float*)d_in[5];
  const float* wb2 = (const float*)d_in[6];
  const float* hW1 = (const float*)d_in[7];
  const float* hb1 = (const float*)d_in[8];
  const float* hW2 = (const float*)d_in[9];
  const float* hb2 = (const float*)d_in[10];
  const float* sW1 = (const float*)d_in[11];
  const float* sb1 = (const float*)d_in[12];
  const float* sW2 = (const float*)d_in[13];
  const float* sb2 = (const float*)d_in[14];

  uint16_t* W2m   = (uint16_t*)((char*)d_ws + W2M_OFF);
  float*    b2all = (float*)((char*)d_ws + B2ALL_OFF);
  uint16_t* W1m   = (uint16_t*)((char*)d_ws + W1M_OFF);
  float*    b1all = (float*)((char*)d_ws + B1_OFF);
  float*    partp = (float*)((char*)d_ws + PART_OFF);

  const int total = W2M_ELEMS + B2ALL_ELEMS + W1M_ELEMS + B1_ELEMS;
  repack_kernel<<<(total + 255)/256, 256, 0, stream>>>(
      wW2, wb2, hW2, hb2, sW2, sb2, wW1, hW1, sW1, wb1, hb1, sb1,
      W2m, b2all, W1m, b1all);

  float* Y = (float*)d_out;
  float* LADJ = Y + (size_t)M_TOTAL*DIMS;
  spline_main<<<(M_TOTAL/ROWS)*2, 256, 0, stream>>>(
      x, cond, pmask, W2m, b2all, W1m, b1all, Y, partp);
  ladj_reduce<<<(M_TOTAL + 255)/256, 256, 0, stream>>>(partp, LADJ);
}

// Round 18
// 58.163 us; speedup vs baseline: 2.1238x; 2.1238x over previous
//
#include <hip/hip_runtime.h>
#include <stdint.h>

#define M_TOTAL 16384
#define DIMS    64
#define CDIM    64
#define HID     100
#define ROWS    32
#define LOG2E   1.4426950408889634f
#define LN2     0.6931471805599453f

typedef __bf16 bf16x8 __attribute__((ext_vector_type(8)));
typedef float  f32x4  __attribute__((ext_vector_type(4)));

// W2 ws layout: [d][cn 0..6][kg 0..13][col16][8] (bf16); w,h cols pre-scaled by log2(e)
#define BKG        14
#define CN_STRIDE  (BKG*16*8)        // 1792
#define DIM_STRIDE (7*CN_STRIDE)     // 12544
#define W2M_ELEMS  (DIMS*DIM_STRIDE) // 802816
#define B2ALL_ELEMS (DIMS*128)       // 8192 f32
#define W1M_ELEMS  (3*7*8*16*8)      // 21504 bf16: [mat][cn][kg8][col16][8]
#define B1_ELEMS   (3*112)           // 336 f32
#define W2M_OFF   0
#define B2ALL_OFF (W2M_ELEMS*2)                  // 1605632
#define W1M_OFF   (B2ALL_OFF + B2ALL_ELEMS*4)    // 1638400
#define B1_OFF    (W1M_OFF + W1M_ELEMS*2)        // 1681408

__device__ __forceinline__ uint16_t f2bf(float f) {
  uint32_t u = __float_as_uint(f);
  return (uint16_t)((u + 0x8000u) >> 16);
}

__global__ void repack_kernel(
    const float* __restrict__ wW2, const float* __restrict__ wb2,
    const float* __restrict__ hW2, const float* __restrict__ hb2,
    const float* __restrict__ sW2, const float* __restrict__ sb2,
    const float* __restrict__ wW1, const float* __restrict__ hW1,
    const float* __restrict__ sW1,
    const float* __restrict__ wb1, const float* __restrict__ hb1,
    const float* __restrict__ sb1,
    uint16_t* __restrict__ W2m, float* __restrict__ b2all,
    uint16_t* __restrict__ W1m, float* __restrict__ b1all)
{
  int i = blockIdx.x * 256 + threadIdx.x;
  if (i < W2M_ELEMS) {
    int j  = i & 7;
    int c  = (i >> 3) & 15;
    int t  = i >> 7;
    int kg = t % BKG;
    int t2 = t / BKG;
    int cn = t2 % 7;
    int d  = t2 / 7;
    int k   = kg*8 + j;
    int col = cn*16 + c;
    float v = 0.f;
    if (k < HID) {
      if (col < 32)      v = wW2[k*2048 + d*32 + col] * LOG2E;
      else if (col < 64) v = hW2[k*2048 + d*32 + (col-32)] * LOG2E;
      else if (col < 97) v = sW2[k*2112 + d*33 + (col-64)];
    }
    W2m[i] = f2bf(v);
    return;
  }
  i -= W2M_ELEMS;
  if (i < B2ALL_ELEMS) {
    int c = i & 127;
    int d = i >> 7;
    float v = 0.f;
    if (c < 32)      v = wb2[d*32 + c] * LOG2E;
    else if (c < 64) v = hb2[d*32 + (c-32)] * LOG2E;
    else if (c < 97) v = sb2[d*33 + (c-64)];
    b2all[i] = v;
    return;
  }
  i -= B2ALL_ELEMS;
  if (i < W1M_ELEMS) {
    int jj = i & 7;
    int c  = (i >> 3) & 15;
    int kg = (i >> 7) & 7;
    int t  = i >> 10;         // mat*7 + cn
    int cn = t % 7;
    int mat = t / 7;
    int j = cn*16 + c;        // hidden unit
    int k = kg*8 + jj;        // cond dim
    const float* W1 = (mat == 0) ? wW1 : (mat == 1) ? hW1 : sW1;
    W1m[i] = f2bf((j < HID) ? W1[k*HID + j] : 0.f);
    return;
  }
  i -= W1M_ELEMS;
  if (i < B1_ELEMS) {
    int mat = i / 112, col = i % 112;
    const float* b1 = (mat == 0) ? wb1 : (mat == 1) ? hb1 : sb1;
    b1all[i] = (col < HID) ? b1[col] : 0.f;
  }
}

__global__ __launch_bounds__(256, 2)
void spline_main(
    const float* __restrict__ X, const float* __restrict__ C,
    const int* __restrict__ pmask,
    const uint16_t* __restrict__ W2m, const float* __restrict__ b2all,
    const uint16_t* __restrict__ W1m, const float* __restrict__ b1all,
    float* __restrict__ Y, float* __restrict__ LADJ)
{
  __shared__ union {
    float cond_s[ROWS*68];       // 8704 B (phase 0/1 only)
    float Ls[4][ROWS*100];       // 51200 B (main loop)
  } U;
  __shared__ uint16_t At[3*16*ROWS*8];  // 24576 B, persistent
  __shared__ float LjLds[4][ROWS];      // 512 B   (total ~76.3 KB)

  const int tid = threadIdx.x;
  const int r0 = blockIdx.x * ROWS;
  const int lane = tid & 63, wv = tid >> 6;
  const int l15 = lane & 15, lkg = lane >> 4;
  const int hb = lane >> 5;          // 0: widths pipe, 1: heights pipe
  const int srow = lane & 31;

  // ---- phase 0: stage cond tile ----
  for (int i = tid; i < ROWS*CDIM; i += 256) {
    int r = i >> 6, c = i & 63;
    U.cond_s[r*68 + c] = C[(size_t)(r0 + r)*CDIM + c];
  }
  __syncthreads();

  // ---- phase 1: hidden = silu(cond@W1+b1) via MFMA -> At (bf16, MFMA A layout) ----
  {
    bf16x8 cf[2][2];
#pragma unroll
    for (int m = 0; m < 2; ++m)
#pragma unroll
      for (int ks = 0; ks < 2; ++ks) {
        const float* cp = &U.cond_s[(m*16 + l15)*68 + ks*32 + lkg*8];
        float4 c0 = *(const float4*)cp;
        float4 c1 = *(const float4*)(cp + 4);
        union { uint16_t u[8]; bf16x8 v; } tmp;
        tmp.u[0]=f2bf(c0.x); tmp.u[1]=f2bf(c0.y); tmp.u[2]=f2bf(c0.z); tmp.u[3]=f2bf(c0.w);
        tmp.u[4]=f2bf(c1.x); tmp.u[5]=f2bf(c1.y); tmp.u[6]=f2bf(c1.z); tmp.u[7]=f2bf(c1.w);
        cf[m][ks] = tmp.v;
      }
    for (int t = wv; t < 21; t += 4) {
      int mat = t / 7, cn = t % 7;
      const uint16_t* Wb = W1m + (size_t)(mat*7 + cn)*1024;
      bf16x8 wf[2];
#pragma unroll
      for (int ks = 0; ks < 2; ++ks)
        wf[ks] = *(const bf16x8*)&Wb[(ks*4 + lkg)*128 + l15*8];
      f32x4 h0 = {0.f,0.f,0.f,0.f}, h1 = {0.f,0.f,0.f,0.f};
#pragma unroll
      for (int ks = 0; ks < 2; ++ks) {
        h0 = __builtin_amdgcn_mfma_f32_16x16x32_bf16(cf[0][ks], wf[ks], h0, 0, 0, 0);
        h1 = __builtin_amdgcn_mfma_f32_16x16x32_bf16(cf[1][ks], wf[ks], h1, 0, 0, 0);
      }
      float bb = b1all[mat*112 + cn*16 + l15];
      int j = cn*16 + l15;
      int base = mat*4096 + (j >> 3)*256 + (j & 7);
#pragma unroll
      for (int r = 0; r < 4; ++r) {
        float a0 = h0[r] + bb;
        float v0 = a0 * __builtin_amdgcn_rcpf(1.f + __builtin_amdgcn_exp2f(-LOG2E*a0));
        At[base + (lkg*4 + r)*8] = f2bf(v0);
        float a1 = h1[r] + bb;
        float v1 = a1 * __builtin_amdgcn_rcpf(1.f + __builtin_amdgcn_exp2f(-LOG2E*a1));
        At[base + (16 + lkg*4 + r)*8] = f2bf(v1);
      }
    }
    // zero-fill At kg 14,15 (K-padding: A must be 0 there)
    for (int i2 = tid; i2 < 768; i2 += 256) {
      int mat = i2 >> 8, q = i2 & 255;
      *(uint32_t*)&At[mat*4096 + 14*256 + q*2] = 0u;
    }
  }
  __syncthreads();   // At complete; cond_s dead -> Ls region writable

  // ---- hoist A fragments for mats 0,1 into registers (64 VGPR); mat 2 per-dim ----
  bf16x8 af01[2][2][4];
#pragma unroll
  for (int mat = 0; mat < 2; ++mat)
#pragma unroll
    for (int m = 0; m < 2; ++m)
#pragma unroll
      for (int ks = 0; ks < 4; ++ks)
        af01[mat][m][ks] = *(const bf16x8*)&At[mat*4096 + (ks*4 + lkg)*256 + (m*16 + l15)*8];

  float* LsW = &U.Ls[wv][0];
  const int dbase = wv*16;
  float ladj2 = 0.f;
  float xq = 0.f; int pq = 0;

  // ---- spline: binary-descent binsearch + tree-path prefix + LDS gather ----
  auto SPLINE = [&](int d, float xv, int pm) {
    const float* Lr = LsW + srow*100 + hb*32;
    float e[32];
#pragma unroll
    for (int q = 0; q < 8; ++q) *(float4*)&e[4*q] = *(const float4*)(Lr + 4*q);
    // partial-sum tree (levels kept)
    float t2[16], t4[8], t8[4], t16[2];
#pragma unroll
    for (int k = 0; k < 16; ++k) t2[k] = e[2*k] + e[2*k+1];
#pragma unroll
    for (int k = 0; k < 8; ++k)  t4[k] = t2[2*k] + t2[2*k+1];
#pragma unroll
    for (int k = 0; k < 4; ++k)  t8[k] = t4[2*k] + t4[2*k+1];
    t16[0] = t8[0] + t8[1]; t16[1] = t8[2] + t8[3];
    float S = t16[0] + t16[1];
    float rs = __builtin_amdgcn_rcpf(S);
    float Aa = (xv + 1.f) * 0.7352941176470588f * S;   // (x+1)/(2*0.68) * S
    float Uq = 0.014705882352941176f * S;              // 0.01/0.68 * S

    // 5-level binary descent: predicate prefix(c) <= Aa - c*Uq is monotone in c
    float T = Aa, p = 0.f, fidx;
    {
      float A = fmaf(-16.f, Uq, T);
      bool c4 = t16[0] <= A;
      p = c4 ? t16[0] : p;  T = c4 ? A : T;

      float n8 = c4 ? t8[2] : t8[0];
      A = fmaf(-8.f, Uq, T);
      float tt = p + n8;
      bool c3 = tt <= A;
      p = c3 ? tt : p;  T = c3 ? A : T;

      float n4 = c4 ? (c3 ? t4[6] : t4[4]) : (c3 ? t4[2] : t4[0]);
      A = fmaf(-4.f, Uq, T);
      tt = p + n4;
      bool c2 = tt <= A;
      p = c2 ? tt : p;  T = c2 ? A : T;

      float n2 = c4 ? (c3 ? (c2 ? t2[14] : t2[12]) : (c2 ? t2[10] : t2[8]))
                    : (c3 ? (c2 ? t2[6]  : t2[4])  : (c2 ? t2[2]  : t2[0]));
      A = fmaf(-2.f, Uq, T);
      tt = p + n2;
      bool c1 = tt <= A;
      p = c1 ? tt : p;  T = c1 ? A : T;

      float n1 = c4 ? (c3 ? (c2 ? (c1 ? e[30] : e[28]) : (c1 ? e[26] : e[24]))
                          : (c2 ? (c1 ? e[22] : e[20]) : (c1 ? e[18] : e[16])))
                    : (c3 ? (c2 ? (c1 ? e[14] : e[12]) : (c1 ? e[10] : e[8]))
                          : (c2 ? (c1 ? e[6]  : e[4])  : (c1 ? e[2]  : e[0])));
      A = fmaf(-1.f, Uq, T);
      bool c0 = (p + n1) <= A;
      fidx = (c4 ? 16.f : 0.f) + (c3 ? 8.f : 0.f) + (c2 ? 4.f : 0.f)
           + (c1 ? 2.f : 0.f) + (c0 ? 1.f : 0.f);
    }
    // broadcast lo-lane idx to both pipes
    float idxu = __shfl(fidx, srow);
    int idxi = (int)idxu;
    // bit extract
    bool B4 = idxu >= 15.5f; float u = B4 ? idxu - 16.f : idxu;
    bool B3 = u >= 7.5f;  u = B3 ? u - 8.f : u;
    bool B2 = u >= 3.5f;  u = B2 ? u - 4.f : u;
    bool B1 = u >= 1.5f;  u = B1 ? u - 2.f : u;
    bool B0 = u >= 0.5f;
    // tree-path prefix assembly at idxu (both pipes, own data)
    float Psel = B4 ? t16[0] : 0.f;
    float q8 = B4 ? t8[2] : t8[0];
    Psel = B3 ? Psel + q8 : Psel;
    float q4 = B4 ? (B3 ? t4[6] : t4[4]) : (B3 ? t4[2] : t4[0]);
    Psel = B2 ? Psel + q4 : Psel;
    float q2 = B4 ? (B3 ? (B2 ? t2[14] : t2[12]) : (B2 ? t2[10] : t2[8]))
                  : (B3 ? (B2 ? t2[6]  : t2[4])  : (B2 ? t2[2]  : t2[0]));
    Psel = B1 ? Psel + q2 : Psel;
    // leaf pair via one dynamic LDS gather: {e[idx&~1], e[idx|1]}
    float2 ep = *(const float2*)(Lr + (idxi & ~1));
    float q1e = ep.x, q1o = ep.y;
    Psel = B0 ? Psel + q1e : Psel;
    float esel = B0 ? q1o : q1e;

    float cK = fmaf(0.02f, idxu, -1.f) + 1.36f*rs*Psel;
    float wK = (idxu > 30.5f) ? (1.f - cK) : fmaf(1.36f*rs, esel, 0.02f);
    // slope: lo takes d[idx], hi takes d[idx+1] (periodic tie at idx==31)
    int off = 64 + idxi + hb;
    if (hb && idxi == 31) off = pm ? 64 : 96;
    float sl = LsW[srow*100 + off];
    float dkv = fmaf(LN2, __builtin_amdgcn_logf(1.f + __builtin_amdgcn_exp2f(LOG2E*sl)), 0.01f);
    // exchange: lo receives hi's (chk, hk, dk1)
    float cO = __shfl_xor(cK, 32);
    float wO = __shfl_xor(wK, 32);
    float dO = __shfl_xor(dkv, 32);
    float cwk = cK, wk = wK, dk = dkv, chk = cO, hk = wO, dk1 = dO;
    float rw = __builtin_amdgcn_rcpf(wk);
    float th = (xv - cwk)*rw;
    float delta = hk*rw;
    float omt = 1.f - th, t1m = th*omt, th2 = th*th;
    float denom = fmaf(dk1 + dk - 2.f*delta, t1m, delta);
    float rden = __builtin_amdgcn_rcpf(denom);
    float yv = fmaf(hk*fmaf(delta, th2, dk*t1m), rden, chk);
    float dn2 = fmaf(dk1, th2, fmaf(2.f*delta, t1m, dk*omt*omt));
    float tq = delta * rden;
    ladj2 += __builtin_amdgcn_logf(tq*tq*dn2);   // = 2log(delta)-2log(denom)+log(dn2)
    if (!hb) Y[(size_t)(r0 + srow)*DIMS + d] = yv;
  };

  // ---- A-frag loader (one mat -> 8 regs) ----
  auto LOADA = [&](bf16x8 (&a2)[2][4], int mat) {
#pragma unroll
    for (int m = 0; m < 2; ++m)
#pragma unroll
      for (int ks = 0; ks < 4; ++ks)
        a2[m][ks] = *(const bf16x8*)&At[mat*4096 + (ks*4 + lkg)*256 + (m*16 + l15)*8];
  };

  // ---- per-cn GEMM tile: 8 MFMA + epilogue ----
  auto DO = [&](const bf16x8 (&afm)[2][4], const bf16x8 (&B)[4],
                float bb, int col, bool doexp) {
    f32x4 a0 = {bb,bb,bb,bb}, a1 = {bb,bb,bb,bb};
#pragma unroll
    for (int ks = 0; ks < 4; ++ks)
      a0 = __builtin_amdgcn_mfma_f32_16x16x32_bf16(afm[0][ks], B[ks], a0, 0, 0, 0);
#pragma unroll
    for (int ks = 0; ks < 4; ++ks)
      a1 = __builtin_amdgcn_mfma_f32_16x16x32_bf16(afm[1][ks], B[ks], a1, 0, 0, 0);
    if (doexp) {
#pragma unroll
      for (int r = 0; r < 4; ++r) {
        a0[r] = __builtin_amdgcn_exp2f(a0[r]);
        a1[r] = __builtin_amdgcn_exp2f(a1[r]);
      }
    }
    if (col < 97) {
#pragma unroll
      for (int r = 0; r < 4; ++r) {
        LsW[(lkg*4 + r)*100 + col]      = a0[r];
        LsW[(16 + lkg*4 + r)*100 + col] = a1[r];
      }
    }
  };

  // ---- main loop: 16 dims per wave, no barriers, 3-deep B pipeline ----
#pragma unroll 1
  for (int dd = 0; dd < 16; ++dd) {
    const int d = dbase + dd;
    const uint16_t* Bd = W2m + (size_t)d*DIM_STRIDE;
    auto LOADB = [&](bf16x8 (&dst)[4], int cn) {
#pragma unroll
      for (int ks = 0; ks < 4; ++ks) {
        int kgb = ks*4 + lkg; kgb = (kgb > 13) ? 13 : kgb;
        dst[ks] = *(const bf16x8*)&Bd[cn*CN_STRIDE + kgb*128 + l15*8];
      }
    };
    bf16x8 bA[4], bB[4], bC[4];
    LOADB(bA, 0); LOADB(bB, 1); LOADB(bC, 2);
    float bbv[7];
#pragma unroll
    for (int cn = 0; cn < 7; ++cn) bbv[cn] = b2all[d*128 + cn*16 + l15];
    float xn = X[(size_t)(r0 + srow)*DIMS + d];
    int pn = pmask[d];

    if (dd > 0) SPLINE(d - 1, xq, pq);   // hides B-load latency
    xq = xn; pq = pn;

    DO(af01[0], bA, bbv[0], 0*16 + l15, true);  LOADB(bA, 3);
    DO(af01[0], bB, bbv[1], 1*16 + l15, true);  LOADB(bB, 4);
    DO(af01[1], bC, bbv[2], 2*16 + l15, true);  LOADB(bC, 5);
    DO(af01[1], bA, bbv[3], 3*16 + l15, true);  LOADB(bA, 6);
    bf16x8 afc[2][4];
    LOADA(afc, 2);
    DO(afc, bB, bbv[4], 4*16 + l15, false);
    DO(afc, bC, bbv[5], 5*16 + l15, false);
    DO(afc, bA, bbv[6], 6*16 + l15, false);
  }
  SPLINE(dbase + 15, xq, pq);

  if (!hb) LjLds[wv][srow] = ladj2;
  __syncthreads();
  if (tid < ROWS)
    LADJ[r0 + tid] = LN2 * ((LjLds[0][tid] + LjLds[1][tid]) + (LjLds[2][tid] + LjLds[3][tid]));
}

extern "C" void kernel_launch(void* const* d_in, const int* in_sizes, int n_in,
                              void* d_out, int out_size, void* d_ws, size_t ws_size,
                              hipStream_t stream) {
  const float* x     = (const float*)d_in[0];
  const float* cond  = (const float*)d_in[1];
  const int*   pmask = (const int*)d_in[2];
  const float* wW1 = (const float*)d_in[3];
  const float* wb1 = (const float*)d_in[4];
  const float* wW2 = (const float*)d_in[5];
  const float* wb2 = (const float*)d_in[6];
  const float* hW1 = (const float*)d_in[7];
  const float* hb1 = (const float*)d_in[8];
  const float* hW2 = (const float*)d_in[9];
  const float* hb2 = (const float*)d_in[10];
  const float* sW1 = (const float*)d_in[11];
  const float* sb1 = (const float*)d_in[12];
  const float* sW2 = (const float*)d_in[13];
  const float* sb2 = (const float*)d_in[14];

  uint16_t* W2m   = (uint16_t*)((char*)d_ws + W2M_OFF);
  float*    b2all = (float*)((char*)d_ws + B2ALL_OFF);
  uint16_t* W1m   = (uint16_t*)((char*)d_ws + W1M_OFF);
  float*    b1all = (float*)((char*)d_ws + B1_OFF);

  const int total = W2M_ELEMS + B2ALL_ELEMS + W1M_ELEMS + B1_ELEMS;
  repack_kernel<<<(total + 255)/256, 256, 0, stream>>>(
      wW2, wb2, hW2, hb2, sW2, sb2, wW1, hW1, sW1, wb1, hb1, sb1,
      W2m, b2all, W1m, b1all);

  float* Y = (float*)d_out;
  float* LADJ = Y + (size_t)M_TOTAL*DIMS;
  spline_main<<<M_TOTAL/ROWS, 256, 0, stream>>>(
      x, cond, pmask, W2m, b2all, W1m, b1all, Y, LADJ);
}